// Round 7
// baseline (3191.593 us; speedup 1.0000x reference)
//
#include <hip/hip_runtime.h>
#include <stdint.h>

// Problem constants
#define Bsz  64
#define Tsz  512
#define NUsz 256
#define NXsz 1024

// Decomposition: 4 groups x 16 batches; 32 WGs per group, 32 columns each;
// 128 WGs total. MB=16 keeps r0's full-M MFMA shape (r3's regression was
// MB=8's wasted M-half); GWG=32 halves per-group exchange fan-in, LLC read
// traffic, and skew (max over 32 producers instead of 64).
#define NGRP 4
#define GWG  32
#define MB   16
#define NC   32

// Sticky watchdog (proven harmless r3/r4/r6): trip once -> skip all later
// waits so any protocol bug terminates fast with wrong data, not a hang.
#define SPIN_MAX (1u << 18)

typedef __attribute__((ext_vector_type(8))) short  short8;
typedef __attribute__((ext_vector_type(4))) float  float4v;
typedef unsigned long long ull;

// Workspace layout (d_ws) -- buffer geometry identical to round-0
#define FLAGX_OFF   0                     // 4 groups x 32 u32
#define FLAGFX_OFF  2048
#define XBUF_OFF    4096
#define XBUF_PG     65536                 // per group: 2 parities x 64 slices x 512 B
#define FXBUF_OFF   (XBUF_OFF + NGRP * XBUF_PG)
// total ws use: 4096 + 2*4*65536 = 528384 bytes

__device__ __forceinline__ short f2bf(float f) {
  unsigned x = __float_as_uint(f);
  return (short)((x + 0x7fffu + ((x >> 16) & 1u)) >> 16);  // RNE f32->bf16
}

// Init: reset flags, stage x0 slices (bf16) into parity-0 x broadcast buffer.
// Plain stores: end-of-kernel L2 writeback makes them LLC-visible before
// gru_persist's agent-scope loads run. (Round-0 verified pattern.)
__global__ void gru_init(const float* __restrict__ x0, unsigned char* __restrict__ ws) {
  unsigned idx = blockIdx.x * 256u + threadIdx.x;   // grid 256 x 256 = 65536
  unsigned* flagx  = (unsigned*)(ws + FLAGX_OFF);
  unsigned* flagfx = (unsigned*)(ws + FLAGFX_OFF);
  if (idx < 128u)                       flagx[idx] = 1u;          // x_0 available
  else if (idx >= 256u && idx < 384u)   flagfx[idx - 256u] = 0u;
  unsigned g = idx >> 14, rem = idx & 16383u;
  unsigned jj = rem >> 8, b = (rem >> 4) & 15u, k = rem & 15u;
  float v = x0[(g * 16u + b) * NXsz + jj * 16u + k];
  *(short*)(ws + XBUF_OFF + g * XBUF_PG + jj * 512u + b * 32u + k * 2u) = f2bf(v);
}

// Poll the group's 32 producer flags: lanes 0..31 one flag each (32..63
// duplicate), relaxed agent-scope loads, wave-wide __all. (r3-verified.)
__device__ __forceinline__ void wait_flags(const unsigned* f, int lane, unsigned need,
                                           unsigned* dead) {
  if (*dead) return;
  const unsigned* p = f + (lane & 31);
  unsigned spins = 0;
  while (true) {
    unsigned v = __hip_atomic_load(p, __ATOMIC_RELAXED, __HIP_MEMORY_SCOPE_AGENT);
    if (__all((int)(v >= need))) break;
    if (++spins > SPIN_MAX) { *dead = 1u; break; }   // sticky trip: fail, don't hang
    __builtin_amdgcn_s_sleep(1);
  }
  // Compiler barrier + waitcnt only (workgroup scope => NO cache ops; data
  // pulls below are agent-scope atomics themselves). Round-0 verified.
  __builtin_amdgcn_fence(__ATOMIC_ACQUIRE, "workgroup");
}

// Load one B-fragment (16 cols starting at `col`, K rows k0..k0+7) from a
// row-major [K][NX] fp32 matrix into a bf16 short8. One-time init cost.
__device__ __forceinline__ short8 ldfragB(const float* __restrict__ U, int col, int k0) {
  short8 s;
  #pragma unroll
  for (int e = 0; e < 8; ++e) s[e] = f2bf(U[(long)(k0 + e) * NXsz + col]);
  return s;
}

#define MFMA(a, b, c) __builtin_amdgcn_mfma_f32_16x16x32_bf16((a), (b), (c), 0, 0, 0)

__launch_bounds__(256, 1)
__global__ void gru_persist(const float* __restrict__ u,  const float* __restrict__ x0,
                            const float* __restrict__ Wz, const float* __restrict__ Uz, const float* __restrict__ bz,
                            const float* __restrict__ Wf, const float* __restrict__ Uf, const float* __restrict__ bfp,
                            const float* __restrict__ Wr, const float* __restrict__ Ur, const float* __restrict__ br,
                            float* __restrict__ out, unsigned char* __restrict__ ws)
{
  // LDS: Uz/Uf column slabs (K chunks 0..30; chunk 31 + all W slabs + the
  // full Ur share live in registers -- r3-verified scheme, NC=32 cols).
  __shared__ short zfU[2][32][1000];           // 128,000 B (row stride 2000 B)
  __shared__ float part[4][2][16][33];         //  16,896 B (padded)
  __shared__ float xs[16][33];                 //   2,112 B fp32 carried state
  __shared__ float bz_s[32], bf_s[32], br_s[32];
  // total ~147.4 KB => 1 WG/CU

  const int bx   = blockIdx.x;                 // 0..127
  const int xcd  = bx & 7;                     // heuristic XCD round-robin swizzle
  const int g    = xcd >> 1;                   // group -> XCD pair {2g,2g+1}
  const int j    = ((xcd & 1) << 4) | (bx >> 3);  // rank 0..31
  const int tid  = threadIdx.x;
  const int wv   = tid >> 6;
  const int lane = tid & 63;
  const int q    = lane >> 4;
  const int cl   = lane & 15;
  const int col0 = j * NC;

  // ---- stage Uz/Uf column slabs (K 0..991) to LDS, bf16 ----
  for (int idx = tid; idx < 2 * 32 * 992; idx += 256) {
    int gate = (idx >= 32 * 992);
    int rem  = idx - gate * (32 * 992);
    int k = rem >> 5, n = rem & 31;
    const float* U = gate ? Uf : Uz;
    zfU[gate][n][k] = f2bf(U[(long)k * NXsz + col0 + n]);
  }
  for (int idx = tid; idx < 512; idx += 256) {
    int b = idx >> 5, n = idx & 31;
    xs[b][n] = x0[(g * MB + b) * NXsz + col0 + n];
  }
  if (tid < 32) {
    bz_s[tid] = bz[col0 + tid];
    bf_s[tid] = bfp[col0 + tid];
    br_s[tid] = br[col0 + tid];
  }

  // ---- per-wave register weights (r3-verified): Ur share, W slabs, zf chunk 31 ----
  const int bc0 = col0 + cl;
  short8 rU[16], rW[4], zW[4], fW[4], zU31[2], fU31[2];
  #pragma unroll
  for (int i = 0; i < 8; ++i) {
    int k0 = (wv * 8 + i) * 32 + q * 8;
    rU[i*2+0] = ldfragB(Ur, bc0,      k0);
    rU[i*2+1] = ldfragB(Ur, bc0 + 16, k0);
  }
  #pragma unroll
  for (int i = 0; i < 2; ++i) {
    int k0 = (wv * 2 + i) * 32 + q * 8;
    rW[i*2+0] = ldfragB(Wr, bc0, k0);  rW[i*2+1] = ldfragB(Wr, bc0+16, k0);
    zW[i*2+0] = ldfragB(Wz, bc0, k0);  zW[i*2+1] = ldfragB(Wz, bc0+16, k0);
    fW[i*2+0] = ldfragB(Wf, bc0, k0);  fW[i*2+1] = ldfragB(Wf, bc0+16, k0);
  }
  if (wv == 3) {
    zU31[0] = ldfragB(Uz, bc0, 992 + q*8);  zU31[1] = ldfragB(Uz, bc0+16, 992 + q*8);
    fU31[0] = ldfragB(Uf, bc0, 992 + q*8);  fU31[1] = ldfragB(Uf, bc0+16, 992 + q*8);
  } else {
    #pragma unroll
    for (int e = 0; e < 8; ++e) { zU31[0][e]=0; zU31[1][e]=0; fU31[0][e]=0; fU31[1][e]=0; }
  }
  __syncthreads();

  unsigned* flagx  = (unsigned*)(ws + FLAGX_OFF)  + g * GWG;
  unsigned* flagfx = (unsigned*)(ws + FLAGFX_OFF) + g * GWG;
  unsigned char* xb_base  = ws + XBUF_OFF  + g * XBUF_PG;
  unsigned char* fxb_base = ws + FXBUF_OFF + g * XBUF_PG;

  // A-fragment address offset within a 32 KB broadcast buffer (r0 verbatim):
  // chunk c: slice = 2c + (q>>1); within slice: row b=cl (32 B), half (q&1)*16
  const unsigned lane_off = (unsigned)(cl * 32 + (q & 1) * 16 + (q >> 1) * 512);

  // Combine / publish pattern: lane -> (batch cb, 8 consecutive cols at cc0).
  const int cb  = lane >> 2;          // 0..15
  const int cc0 = (lane & 3) << 3;    // 0,8,16,24
  // Publish byte offset inside a 32 KB buffer: local cols cc0..cc0+7 live in
  // slice 2j + (cc0>>4), rows 32 B, 16-B aligned contiguous region.
  const unsigned pub_off = (unsigned)((2*j + (cc0 >> 4)) * 512 + cb * 32 + (cc0 & 15) * 2);

  const long uTN = (long)Tsz * NUsz;
  const float* u_row = u + (long)(g * MB + cl) * uTN;  // A row m = cl

  float zreg[8];
  #pragma unroll
  for (int i = 0; i < 8; ++i) zreg[i] = 0.f;
  unsigned dead = 0;

  for (int t = 0; t < Tsz; ++t) {
    const int p = t & 1;
    const unsigned char* xb  = xb_base  + p * 32768;
    unsigned char*       fxb = fxb_base + p * 32768;

    // out[b][t][cols] = x_t  (wave 2; xs stable between s4(prev) and s4)
    if (wv == 2) {
      float* op = out + (long)(g * MB + cb) * ((long)Tsz * NXsz) + (long)t * NXsz + col0 + cc0;
      float4v o0 = { xs[cb][cc0],   xs[cb][cc0+1], xs[cb][cc0+2], xs[cb][cc0+3] };
      float4v o1 = { xs[cb][cc0+4], xs[cb][cc0+5], xs[cb][cc0+6], xs[cb][cc0+7] };
      *(float4v*)op = o0;
      *(float4v*)(op + 4) = o1;
    }

    // ---- flag-independent work first: u-projection fragments + W MFMAs ----
    short8 au[2];
    #pragma unroll
    for (int i = 0; i < 2; ++i) {
      const float* up = u_row + (long)t * NUsz + (wv * 2 + i) * 32 + q * 8;
      float4v u0 = *(const float4v*)up;
      float4v u1 = *(const float4v*)(up + 4);
      short8 s;
      s[0]=f2bf(u0[0]); s[1]=f2bf(u0[1]); s[2]=f2bf(u0[2]); s[3]=f2bf(u0[3]);
      s[4]=f2bf(u1[0]); s[5]=f2bf(u1[1]); s[6]=f2bf(u1[2]); s[7]=f2bf(u1[3]);
      au[i] = s;
    }
    float4v az0 = {0,0,0,0}, az1 = {0,0,0,0}, af0 = {0,0,0,0}, af1 = {0,0,0,0};
    #pragma unroll
    for (int i = 0; i < 2; ++i) {
      az0 = MFMA(au[i], zW[i*2+0], az0);
      az1 = MFMA(au[i], zW[i*2+1], az1);
      af0 = MFMA(au[i], fW[i*2+0], af0);
      af1 = MFMA(au[i], fW[i*2+1], af1);
    }

    // ---- phase 1: wait full x_t, accumulate x@Uz, x@Uf (both col halves) ----
    wait_flags(flagx, lane, (unsigned)(t + 1), &dead);
    {
      ull ax[16];
      #pragma unroll
      for (int i = 0; i < 8; ++i) {
        const ull* pp = (const ull*)(xb + lane_off + (unsigned)((wv * 8 + i) * 1024));
        ax[2*i]   = __hip_atomic_load(pp,     __ATOMIC_RELAXED, __HIP_MEMORY_SCOPE_AGENT);
        ax[2*i+1] = __hip_atomic_load(pp + 1, __ATOMIC_RELAXED, __HIP_MEMORY_SCOPE_AGENT);
      }
      #pragma unroll
      for (int i = 0; i < 8; ++i) {
        union { ull u2[2]; short8 s8; } cv;
        cv.u2[0] = ax[2*i]; cv.u2[1] = ax[2*i+1];
        const int c = wv * 8 + i;
        short8 b00, b01, b10, b11;
        if (i == 7) {
          int koff = ((wv == 3) ? 0 : c*32) + q*8;   // keep LDS index in-bounds
          b00 = *(const short8*)&zfU[0][cl][koff];
          b01 = *(const short8*)&zfU[0][cl+16][koff];
          b10 = *(const short8*)&zfU[1][cl][koff];
          b11 = *(const short8*)&zfU[1][cl+16][koff];
          if (wv == 3) { b00 = zU31[0]; b01 = zU31[1]; b10 = fU31[0]; b11 = fU31[1]; }
        } else {
          int koff = c*32 + q*8;
          b00 = *(const short8*)&zfU[0][cl][koff];
          b01 = *(const short8*)&zfU[0][cl+16][koff];
          b10 = *(const short8*)&zfU[1][cl][koff];
          b11 = *(const short8*)&zfU[1][cl+16][koff];
        }
        az0 = MFMA(cv.s8, b00, az0);
        az1 = MFMA(cv.s8, b01, az1);
        af0 = MFMA(cv.s8, b10, af0);
        af1 = MFMA(cv.s8, b11, af1);
      }
    }
    #pragma unroll
    for (int r = 0; r < 4; ++r) {
      part[wv][0][q*4+r][cl]      = az0[r];
      part[wv][0][q*4+r][cl + 16] = az1[r];
      part[wv][1][q*4+r][cl]      = af0[r];
      part[wv][1][q*4+r][cl + 16] = af1[r];
    }
    __syncthreads();  // s1

    if (wv == 0) {            // z gate -> registers (8 cols per lane)
      #pragma unroll
      for (int jj2 = 0; jj2 < 8; ++jj2) {
        int c = cc0 + jj2;
        float s = part[0][0][cb][c] + part[1][0][cb][c] + part[2][0][cb][c] + part[3][0][cb][c] + bz_s[c];
        zreg[jj2] = 1.f / (1.f + __expf(-s));
      }
    } else if (wv == 1) {     // f gate -> publish f*x slice (two 8-B atomics)
      ull pk0 = 0, pk1 = 0;
      #pragma unroll
      for (int jj2 = 0; jj2 < 8; ++jj2) {
        int c = cc0 + jj2;
        float s = part[0][1][cb][c] + part[1][1][cb][c] + part[2][1][cb][c] + part[3][1][cb][c] + bf_s[c];
        float f = 1.f / (1.f + __expf(-s));
        ull h = (ull)(unsigned short)f2bf(f * xs[cb][c]);
        if (jj2 < 4) pk0 |= h << (16 * jj2);
        else         pk1 |= h << (16 * (jj2 - 4));
      }
      ull* dp = (ull*)(fxb + pub_off);
      __hip_atomic_store(dp,     pk0, __ATOMIC_RELAXED, __HIP_MEMORY_SCOPE_AGENT);
      __hip_atomic_store(dp + 1, pk1, __ATOMIC_RELAXED, __HIP_MEMORY_SCOPE_AGENT);
      __builtin_amdgcn_fence(__ATOMIC_RELEASE, "workgroup");  // vmcnt(0): data at LLC
      if (lane == 0)
        __hip_atomic_store(flagfx + j, (unsigned)(t + 1), __ATOMIC_RELAXED, __HIP_MEMORY_SCOPE_AGENT);
    }
    __syncthreads();  // s2

    // ---- phase 2: r = tanh(ar + (f.x)@Ur); x_next; publish x slice ----
    float4v ar0 = {0,0,0,0}, ar1 = {0,0,0,0};
    #pragma unroll
    for (int i = 0; i < 2; ++i) {
      ar0 = MFMA(au[i], rW[i*2+0], ar0);
      ar1 = MFMA(au[i], rW[i*2+1], ar1);
    }
    wait_flags(flagfx, lane, (unsigned)(t + 1), &dead);
    {
      ull ax[16];
      #pragma unroll
      for (int i = 0; i < 8; ++i) {
        const ull* pp = (const ull*)(fxb + lane_off + (unsigned)((wv * 8 + i) * 1024));
        ax[2*i]   = __hip_atomic_load(pp,     __ATOMIC_RELAXED, __HIP_MEMORY_SCOPE_AGENT);
        ax[2*i+1] = __hip_atomic_load(pp + 1, __ATOMIC_RELAXED, __HIP_MEMORY_SCOPE_AGENT);
      }
      #pragma unroll
      for (int i = 0; i < 8; ++i) {
        union { ull u2[2]; short8 s8; } cv;
        cv.u2[0] = ax[2*i]; cv.u2[1] = ax[2*i+1];
        ar0 = MFMA(cv.s8, rU[i*2+0], ar0);
        ar1 = MFMA(cv.s8, rU[i*2+1], ar1);
      }
    }
    #pragma unroll
    for (int r = 0; r < 4; ++r) {
      part[wv][0][q*4+r][cl]      = ar0[r];
      part[wv][0][q*4+r][cl + 16] = ar1[r];
    }
    __syncthreads();  // s3

    if (wv == 0) {            // combine + publish x_{t+1}
      unsigned char* xbn = xb_base + ((t + 1) & 1) * 32768;
      ull pk0 = 0, pk1 = 0;
      float xnv[8];
      #pragma unroll
      for (int jj2 = 0; jj2 < 8; ++jj2) {
        int c = cc0 + jj2;
        float s = part[0][0][cb][c] + part[1][0][cb][c] + part[2][0][cb][c] + part[3][0][cb][c] + br_s[c];
        s = fminf(fmaxf(s, -15.f), 15.f);
        float e  = __expf(2.f * s);
        float rr = (e - 1.f) / (e + 1.f);            // tanh
        float xn = zreg[jj2] * xs[cb][c] + (1.f - zreg[jj2]) * rr;
        xnv[jj2] = xn;
        ull h = (ull)(unsigned short)f2bf(xn);
        if (jj2 < 4) pk0 |= h << (16 * jj2);
        else         pk1 |= h << (16 * (jj2 - 4));
      }
      // Issue the LLC stores FIRST, overlap flight with the xs LDS update.
      ull* dp = (ull*)(xbn + pub_off);
      __hip_atomic_store(dp,     pk0, __ATOMIC_RELAXED, __HIP_MEMORY_SCOPE_AGENT);
      __hip_atomic_store(dp + 1, pk1, __ATOMIC_RELAXED, __HIP_MEMORY_SCOPE_AGENT);
      #pragma unroll
      for (int jj2 = 0; jj2 < 8; ++jj2) xs[cb][cc0 + jj2] = xnv[jj2];
      __builtin_amdgcn_fence(__ATOMIC_RELEASE, "workgroup");
      if (lane == 0)
        __hip_atomic_store(flagx + j, (unsigned)(t + 2), __ATOMIC_RELAXED, __HIP_MEMORY_SCOPE_AGENT);
    }
    __syncthreads();  // s4
  }
}

extern "C" void kernel_launch(void* const* d_in, const int* in_sizes, int n_in,
                              void* d_out, int out_size, void* d_ws, size_t ws_size,
                              hipStream_t stream) {
  (void)in_sizes; (void)n_in; (void)out_size; (void)ws_size;
  const float* u   = (const float*)d_in[0];
  const float* x0  = (const float*)d_in[1];
  const float* Wz  = (const float*)d_in[2];
  const float* Uz  = (const float*)d_in[3];
  const float* bz  = (const float*)d_in[4];
  const float* Wf  = (const float*)d_in[5];
  const float* Uf  = (const float*)d_in[6];
  const float* bfp = (const float*)d_in[7];
  const float* Wr  = (const float*)d_in[8];
  const float* Ur  = (const float*)d_in[9];
  const float* br  = (const float*)d_in[10];
  float* out = (float*)d_out;
  unsigned char* ws = (unsigned char*)d_ws;

  hipLaunchKernelGGL(gru_init, dim3(256), dim3(256), 0, stream, x0, ws);

  void* args[] = { (void*)&u, (void*)&x0, (void*)&Wz, (void*)&Uz, (void*)&bz,
                   (void*)&Wf, (void*)&Uf, (void*)&bfp,
                   (void*)&Wr, (void*)&Ur, (void*)&br, (void*)&out, (void*)&ws };
  hipError_t e = hipLaunchCooperativeKernel((const void*)gru_persist, dim3(128), dim3(256),
                                            args, 0, stream);
  if (e != hipSuccess) {
    // Fallback: plain launch (1 WG/CU by LDS limit; 128 blocks co-resident)
    hipLaunchKernelGGL(gru_persist, dim3(128), dim3(256), 0, stream,
                       u, x0, Wz, Uz, bz, Wf, Uf, bfp, Wr, Ur, br, out, ws);
  }
}